// Round 15
// baseline (4676.234 us; speedup 1.0000x reference)
//
#include <hip/hip_runtime.h>
#include <hip/hip_cooperative_groups.h>
#include <math.h>

namespace cg = cooperative_groups;

// ---------------- problem constants ----------------
// B=32 in chunks of nb (adaptive by ws_size), L=244, C=128, F=64, KS=5
// conv lengths: 244 -> 240 -> 236 -> 232 -> 228 ; S=76 ; F3=192 ; D_SA=64
// HID=512, 3*HID=1536 ; big GEMM: M=2432, K=8192, N=1536 (split-K=2)
// R15 = R14 with (a) gemm reverted to proven ns=2, (b) GRU as ONE persistent
// cooperative kernel (grid.sync between the 76 steps) -> launch count ~105->31.
// Per-step math identical -> absmax 0.005859375 expected.

typedef __attribute__((ext_vector_type(8))) short short8;
typedef __attribute__((ext_vector_type(4))) float f32x4;

#define XG_STRIDE 3735552ull   // 2432*1536 floats per split-K partial

__device__ inline float sigm(float x){ return 1.f/(1.f+__expf(-x)); }
__device__ inline unsigned short f2bf(float f){
    unsigned int u = __float_as_uint(f);
    u = (u + 0x7FFFu + ((u >> 16) & 1u)) >> 16;
    return (unsigned short)u;
}
__device__ inline float bf2f(unsigned short h){
    return __uint_as_float(((unsigned int)h) << 16);
}
// bijective chunked XCD swizzle (m204): contiguous work ranges per XCD
__device__ inline int xcd_chunked(int orig, int nwg){
    int q = nwg >> 3, r = nwg & 7;
    int xcd = orig & 7, i = orig >> 3;
    return (xcd < r ? xcd*(q+1) : r*(q+1) + (xcd-r)*q) + i;
}

// ---------------- conv1: x[b][l][c] fp32 -> h1 pair [b][l][c][f] -----------
__global__ __launch_bounds__(256) void conv1_k(const float* __restrict__ x,
        unsigned short* __restrict__ out_h, unsigned short* __restrict__ out_l,
        const float* __restrict__ w1, const float* __restrict__ b1, int b_base)
{
    __shared__ float w1s[320];
    __shared__ float b1s[64];
    int t = threadIdx.x;
    for (int idx = t; idx < 320; idx += 256) w1s[idx] = w1[idx];
    if (t < 64)  b1s[t] = b1[t];
    __syncthreads();
    int i = blockIdx.x*256 + t;          // < nb*240*128
    int c = i & 127; int t2 = i >> 7;
    int l = t2 % 240; int b = t2 / 240;
    const float* xp = x + ((size_t)(b_base + b)*244 + l)*128 + c;
    float xv[5];
    #pragma unroll
    for (int k=0;k<5;++k) xv[k] = xp[k*128];
    unsigned short* oh = out_h + (size_t)i*64;
    unsigned short* ol = out_l + (size_t)i*64;
    #pragma unroll
    for (int f8=0; f8<8; ++f8){
        unsigned short rh[8], rl[8];
        #pragma unroll
        for (int j=0;j<8;++j){
            int f = f8*8 + j;
            float a = b1s[f];
            #pragma unroll
            for (int k=0;k<5;++k) a += w1s[f*5+k]*xv[k];
            a = a > 0.f ? a : 0.f;
            unsigned short hi = f2bf(a);
            rh[j] = hi;
            rl[j] = f2bf(a - bf2f(hi));
        }
        *(short8*)(oh + f8*8) = *(short8*)rh;
        *(short8*)(ol + f8*8) = *(short8*)rl;
    }
}

// ---------------- conv weight repack pairs: [layer][k][fo][fi] -------------
__global__ __launch_bounds__(256) void repack_convw_k(const float* __restrict__ w2,
        const float* __restrict__ w3, const float* __restrict__ w4,
        unsigned short* __restrict__ wbf_h, unsigned short* __restrict__ wbf_l)
{
    int idx = blockIdx.x*256 + threadIdx.x;   // < 61440
    int fi = idx & 63; int t2 = idx >> 6;
    int fo = t2 & 63;  int t3 = t2 >> 6;
    int k = t3 % 5;    int layer = t3 / 5;
    const float* ws_ = (layer==0)? w2 : (layer==1)? w3 : w4;
    float v = ws_[(fo*64 + fi)*5 + k];
    unsigned short hi = f2bf(v);
    wbf_h[idx] = hi;
    wbf_l[idx] = f2bf(v - bf2f(hi));
}

// ---------------- conv2/3/4 split MFMA (R12-proven body, swizzled 1D grid) -
__global__ __launch_bounds__(256) void conv_mfma_s(
        const unsigned short* __restrict__ in_h, const unsigned short* __restrict__ in_l,
        unsigned short* __restrict__ out_h, unsigned short* __restrict__ out_l,
        const unsigned short* __restrict__ wk_h, const unsigned short* __restrict__ wk_l,
        const float* __restrict__ bias, int Lin, int Lout)
{
    __shared__ __align__(16) unsigned short Abh[64*72], Abl[64*72];
    __shared__ __align__(16) unsigned short Wbh[64*72], Wbl[64*72];
    int nblk = gridDim.x;
    int lin = xcd_chunked(blockIdx.x, nblk);
    int ch = lin & 1; int rest = lin >> 1;
    int l = rest % Lout; int b = rest / Lout;

    int t = threadIdx.x;
    int lane = t & 63, w = t >> 6;
    int lr = lane & 15, lh = lane >> 4;
    f32x4 acc[4];
    #pragma unroll
    for (int nf=0;nf<4;++nf) acc[nf] = (f32x4)0.f;

    const size_t ib = ((size_t)b*Lin + l)*8192 + (size_t)ch*4096;
    for (int k=0;k<5;++k){
        __syncthreads();
        #pragma unroll
        for (int i=0;i<2;++i){
            int idx = i*256 + t; int row = idx>>3, c8 = idx&7;
            *(short8*)&Abh[row*72 + c8*8] = *(const short8*)(in_h + ib + (size_t)k*8192 + idx*8);
            *(short8*)&Abl[row*72 + c8*8] = *(const short8*)(in_l + ib + (size_t)k*8192 + idx*8);
        }
        #pragma unroll
        for (int i=0;i<2;++i){
            int idx = i*256 + t; int row = idx>>3, c8 = idx&7;
            *(short8*)&Wbh[row*72 + c8*8] = *(const short8*)(wk_h + k*4096 + idx*8);
            *(short8*)&Wbl[row*72 + c8*8] = *(const short8*)(wk_l + k*4096 + idx*8);
        }
        __syncthreads();
        #pragma unroll
        for (int kk=0;kk<2;++kk){
            short8 ah, al, bh[4], blo[4];
            ah = *(const short8*)&Abh[(w*16+lr)*72 + kk*32 + lh*8];
            al = *(const short8*)&Abl[(w*16+lr)*72 + kk*32 + lh*8];
            #pragma unroll
            for (int nf=0;nf<4;++nf){
                bh[nf]  = *(const short8*)&Wbh[(nf*16+lr)*72 + kk*32 + lh*8];
                blo[nf] = *(const short8*)&Wbl[(nf*16+lr)*72 + kk*32 + lh*8];
            }
            #pragma unroll
            for (int nf=0;nf<4;++nf){
                acc[nf] = __builtin_amdgcn_mfma_f32_16x16x32_bf16(ah, bh[nf],  acc[nf], 0,0,0);
                acc[nf] = __builtin_amdgcn_mfma_f32_16x16x32_bf16(ah, blo[nf], acc[nf], 0,0,0);
                acc[nf] = __builtin_amdgcn_mfma_f32_16x16x32_bf16(al, bh[nf],  acc[nf], 0,0,0);
            }
        }
    }
    const size_t ob = ((size_t)b*Lout + l)*8192;
    #pragma unroll
    for (int nf=0;nf<4;++nf){
        int fo = nf*16 + lr;
        float bv = bias[fo];
        #pragma unroll
        for (int q=0;q<4;++q){
            int c = ch*64 + w*16 + lh*4 + q;
            float v = acc[nf][q] + bv;
            v = v > 0.f ? v : 0.f;
            unsigned short hi = f2bf(v);
            out_h[ob + c*64 + fo] = hi;
            out_l[ob + c*64 + fo] = f2bf(v - bf2f(hi));
        }
    }
}

// ---------------- attention weight repack pairs: [md][jj*64+f] -------------
__global__ __launch_bounds__(256) void repack_wrep_k(const float* __restrict__ wq,
        const float* __restrict__ wk, const float* __restrict__ wv,
        const float* __restrict__ wv1,
        unsigned short* __restrict__ wr_h, unsigned short* __restrict__ wr_l)
{
    int idx = blockIdx.x*256 + threadIdx.x;   // < 256*192
    int ko = idx % 192; int md = idx / 192;
    int m = md >> 6, d = md & 63;
    int jj = ko >> 6, f = ko & 63;
    const float* src = (m==0)? wq : (m==1)? wk : (m==2)? wv : wv1;
    float v = src[d*192 + f*3 + jj];
    unsigned short hi = f2bf(v);
    wr_h[idx] = hi;
    wr_l[idx] = f2bf(v - bf2f(hi));
}

// ---------------- projection split MFMA (R12-proven body, swizzled 1D) -----
__global__ __launch_bounds__(256) void project_mfma_s(
        const unsigned short* __restrict__ h_h, const unsigned short* __restrict__ h_l,
        const unsigned short* __restrict__ wr_h, const unsigned short* __restrict__ wr_l,
        float* __restrict__ Fo, float* __restrict__ Go,
        float* __restrict__ Vo, float* __restrict__ V1o)
{
    __shared__ __align__(16) unsigned short Abh[64*72], Abl[64*72];
    __shared__ __align__(16) unsigned short Bbh[64*72], Bbl[64*72];
    int nblk = gridDim.x;
    int lin = xcd_chunked(blockIdx.x, nblk);
    int z = lin & 7; int rest = lin >> 3;
    int s = rest % 76; int bl = rest / 76;
    int mz = z >> 1, mh = z & 1;

    int t = threadIdx.x;
    int lane = t & 63, w = t >> 6;
    int wm = w >> 1, wn = w & 1;
    int lr = lane & 15, lh = lane >> 4;
    f32x4 acc[2][2];
    #pragma unroll
    for (int mf=0;mf<2;++mf)
        #pragma unroll
        for (int nf=0;nf<2;++nf) acc[mf][nf] = (f32x4)0.f;

    for (int jj=0;jj<3;++jj){
        __syncthreads();
        const size_t ao_ = ((size_t)bl*228 + 3*s + jj)*8192 + (size_t)mh*4096;
        #pragma unroll
        for (int i=0;i<2;++i){
            int idx = i*256 + t; int row = idx>>3, c8 = idx&7;
            *(short8*)&Abh[row*72 + c8*8] = *(const short8*)(h_h + ao_ + idx*8);
            *(short8*)&Abl[row*72 + c8*8] = *(const short8*)(h_l + ao_ + idx*8);
        }
        #pragma unroll
        for (int i=0;i<2;++i){
            int idx = i*256 + t; int row = idx>>3, c8 = idx&7;
            size_t wo = (size_t)(mz*64 + row)*192 + jj*64 + c8*8;
            *(short8*)&Bbh[row*72 + c8*8] = *(const short8*)(wr_h + wo);
            *(short8*)&Bbl[row*72 + c8*8] = *(const short8*)(wr_l + wo);
        }
        __syncthreads();
        #pragma unroll
        for (int kk=0;kk<2;++kk){
            short8 ah[2], al[2], bh[2], blo[2];
            #pragma unroll
            for (int mf=0;mf<2;++mf){
                ah[mf] = *(const short8*)&Abh[(wm*32+mf*16+lr)*72 + kk*32 + lh*8];
                al[mf] = *(const short8*)&Abl[(wm*32+mf*16+lr)*72 + kk*32 + lh*8];
            }
            #pragma unroll
            for (int nf=0;nf<2;++nf){
                bh[nf]  = *(const short8*)&Bbh[(wn*32+nf*16+lr)*72 + kk*32 + lh*8];
                blo[nf] = *(const short8*)&Bbl[(wn*32+nf*16+lr)*72 + kk*32 + lh*8];
            }
            #pragma unroll
            for (int mf=0;mf<2;++mf)
                #pragma unroll
                for (int nf=0;nf<2;++nf){
                    acc[mf][nf] = __builtin_amdgcn_mfma_f32_16x16x32_bf16(ah[mf], bh[nf],  acc[mf][nf], 0,0,0);
                    acc[mf][nf] = __builtin_amdgcn_mfma_f32_16x16x32_bf16(ah[mf], blo[nf], acc[mf][nf], 0,0,0);
                    acc[mf][nf] = __builtin_amdgcn_mfma_f32_16x16x32_bf16(al[mf], bh[nf],  acc[mf][nf], 0,0,0);
                }
        }
    }
    float* dst = (mz==0)? Fo : (mz==1)? Go : (mz==2)? Vo : V1o;
    size_t bs = (size_t)bl*76 + s;
    #pragma unroll
    for (int mf=0;mf<2;++mf)
        #pragma unroll
        for (int nf=0;nf<2;++nf){
            int d = wn*32 + nf*16 + lr;
            int c0 = mh*64 + wm*32 + mf*16 + lh*4;
            *(f32x4*)&dst[(bs*64 + d)*128 + c0] = acc[mf][nf];
        }
}

// ---------------- attention, fp32, 64KB LDS (R7-proven) --------------------
__global__ __launch_bounds__(256) void attend_k(const float* __restrict__ Fg,
        const float* __restrict__ Gg, const float* __restrict__ Vg,
        const float* __restrict__ V1g, const float* __restrict__ gamma,
        unsigned short* __restrict__ seq_bf, int b_base)
{
    __shared__ float sm[16384];    // exactly 64 KB
    int t = threadIdx.x;
    int s = blockIdx.x, bl = blockIdx.y;
    size_t base = ((size_t)bl*76 + s)*8192;
    for (int i=t; i<8192; i+=256) sm[i]      = Fg[base+i];
    for (int i=t; i<8192; i+=256) sm[8192+i] = Gg[base+i];
    __syncthreads();

    int k = t & 127, ch = t >> 7;
    float sc[64];
    #pragma unroll
    for (int j=0;j<64;++j) sc[j]=0.f;
    for (int d=0; d<64; ++d){
        float gk = sm[8192 + d*128 + k];
        #pragma unroll
        for (int cj=0; cj<16; ++cj){
            float4 f4 = *(const float4*)&sm[d*128 + ch*64 + cj*4];
            sc[cj*4+0] += f4.x*gk; sc[cj*4+1] += f4.y*gk;
            sc[cj*4+2] += f4.z*gk; sc[cj*4+3] += f4.w*gk;
        }
    }
    __syncthreads();
    float m = -1e30f;
    #pragma unroll
    for (int j=0;j<64;++j) m = fmaxf(m, sc[j]);
    sm[t] = m;
    for (int i=t; i<8192; i+=256) sm[8192+i] = Vg[base+i];
    __syncthreads();
    m = fmaxf(sm[k], sm[128+k]);
    float lsum = 0.f;
    #pragma unroll
    for (int j=0;j<64;++j){ sc[j] = __expf(sc[j]-m); lsum += sc[j]; }
    __syncthreads();
    sm[t] = lsum;
    __syncthreads();
    float rinv = 1.f/(sm[k] + sm[128+k]);
    #pragma unroll
    for (int j=0;j<64;++j) sc[j] *= rinv;
    __syncthreads();

    if (ch == 0){
        #pragma unroll
        for (int j=0;j<64;++j) sm[j*128 + k] = sc[j];
    }
    __syncthreads();

    int k2 = t & 31, dq = t >> 5;
    float ao[8][4];
    #pragma unroll
    for (int j=0;j<8;++j)
        #pragma unroll
        for (int mm=0;mm<4;++mm) ao[j][mm]=0.f;

    for (int c2=0; c2<64; ++c2){
        float bv0 = sm[c2*128 + k2],    bv1 = sm[c2*128 + k2+32];
        float bv2 = sm[c2*128 + k2+64], bv3 = sm[c2*128 + k2+96];
        #pragma unroll
        for (int j=0;j<8;++j){
            float v = sm[8192 + (dq*8+j)*128 + c2];
            ao[j][0]+=v*bv0; ao[j][1]+=v*bv1; ao[j][2]+=v*bv2; ao[j][3]+=v*bv3;
        }
    }
    __syncthreads();
    if (ch == 1){
        #pragma unroll
        for (int j=0;j<64;++j) sm[j*128 + k] = sc[j];
    }
    __syncthreads();
    for (int c2=64; c2<128; ++c2){
        float bv0 = sm[(c2-64)*128 + k2],    bv1 = sm[(c2-64)*128 + k2+32];
        float bv2 = sm[(c2-64)*128 + k2+64], bv3 = sm[(c2-64)*128 + k2+96];
        #pragma unroll
        for (int j=0;j<8;++j){
            float v = sm[8192 + (dq*8+j)*128 + c2];
            ao[j][0]+=v*bv0; ao[j][1]+=v*bv1; ao[j][2]+=v*bv2; ao[j][3]+=v*bv3;
        }
    }

    float gm = gamma[0];
    size_t sbase = (size_t)(s*32 + b_base + bl)*8192;
    #pragma unroll
    for (int j=0;j<8;++j){
        int d = dq*8+j;
        #pragma unroll
        for (int mm=0;mm<4;++mm){
            int kk = k2 + 32*mm;
            float val = gm*ao[j][mm] + V1g[base + (size_t)d*128 + kk];
            seq_bf[sbase + (size_t)d*128 + kk] = f2bf(val);
        }
    }
}

// ---------------- wih -> bf16 (identity) -----------------------------------
__global__ __launch_bounds__(256) void conv_wih_bf16(const float* __restrict__ w,
        unsigned short* __restrict__ o)
{
    int i = (blockIdx.x*256 + threadIdx.x)*4;   // < 1536*8192
    float4 v = *(const float4*)&w[i];
    ushort4 r;
    r.x = f2bf(v.x); r.y = f2bf(v.y); r.z = f2bf(v.z); r.w = f2bf(v.w);
    *(ushort4*)&o[i] = r;
}

// ---------------- big GEMM bf16 MFMA: 128x128, split-K partials (R11) ------
__global__ __launch_bounds__(512) void gemm_xg_mfma(const unsigned short* __restrict__ A,
        const unsigned short* __restrict__ Bw, const float* __restrict__ bih,
        float* __restrict__ out, int nsplit)
{
    __shared__ float AsF[128*36];
    __shared__ float BsF[128*36];
    int nwg = 228*nsplit;
    int wgid = xcd_chunked(blockIdx.x, nwg);
    int kz = wgid / 228;
    int r2 = wgid % 228;
    int n0 = (r2 % 12) * 128, m0 = (r2 / 12) * 128;   // m-major per XCD
    int klen = 8192 / nsplit;
    int kbase = kz * klen;
    int nkt = klen >> 6;

    int t = threadIdx.x;
    int w = t >> 6;                    // 0..7
    int wm = w >> 1, wn = w & 1;       // 4 x 2 wave grid; wave owns 32x64
    int lane = t & 63, lr = lane & 15, lh = lane >> 4;

    f32x4 acc[2][4];
    #pragma unroll
    for (int mi=0;mi<2;++mi)
        #pragma unroll
        for (int ni=0;ni<4;++ni) acc[mi][ni] = (f32x4)0.f;

    float4 ra[2], rb[2];
    #pragma unroll
    for (int i=0;i<2;++i){
        int idx = i*512 + t; int row = idx>>3, seg = idx&7;
        ra[i] = *(const float4*)(A  + (size_t)(m0 + row)*8192 + kbase + seg*8);
        rb[i] = *(const float4*)(Bw + (size_t)(n0 + row)*8192 + kbase + seg*8);
    }
    for (int kt=0; kt<nkt; ++kt){
        __syncthreads();
        #pragma unroll
        for (int i=0;i<2;++i){
            int idx = i*512 + t; int row = idx>>3, seg = idx&7;
            *(float4*)&AsF[row*36 + seg*4] = ra[i];
            *(float4*)&BsF[row*36 + seg*4] = rb[i];
        }
        __syncthreads();
        if (kt < nkt-1){
            int k0 = kbase + (kt+1)*64;
            #pragma unroll
            for (int i=0;i<2;++i){
                int idx = i*512 + t; int row = idx>>3, seg = idx&7;
                ra[i] = *(const float4*)(A  + (size_t)(m0 + row)*8192 + k0 + seg*8);
                rb[i] = *(const float4*)(Bw + (size_t)(n0 + row)*8192 + k0 + seg*8);
            }
        }
        #pragma unroll
        for (int kk=0;kk<2;++kk){
            short8 af[2], bf_[4];
            #pragma unroll
            for (int mi=0;mi<2;++mi)
                af[mi] = *(short8*)&AsF[(wm*32 + mi*16 + lr)*36 + kk*16 + lh*4];
            #pragma unroll
            for (int ni=0;ni<4;++ni)
                bf_[ni] = *(short8*)&BsF[(wn*64 + ni*16 + lr)*36 + kk*16 + lh*4];
            // operand-swapped: D fragment = C^T tile -> lane holds consecutive n
            #pragma unroll
            for (int mi=0;mi<2;++mi)
                #pragma unroll
                for (int ni=0;ni<4;++ni)
                    acc[mi][ni] = __builtin_amdgcn_mfma_f32_16x16x32_bf16(
                                      bf_[ni], af[mi], acc[mi][ni], 0, 0, 0);
        }
    }
    float* op = out + (size_t)kz*XG_STRIDE;
    #pragma unroll
    for (int ni=0;ni<4;++ni){
        int nbase = n0 + wn*64 + ni*16 + lh*4;
        float4 bi4 = (kz == 0) ? *(const float4*)&bih[nbase]
                               : make_float4(0.f,0.f,0.f,0.f);
        #pragma unroll
        for (int mi=0;mi<2;++mi){
            int m = m0 + wm*32 + mi*16 + lr;
            float4 o;
            o.x = acc[mi][ni][0] + bi4.x;
            o.y = acc[mi][ni][1] + bi4.y;
            o.z = acc[mi][ni][2] + bi4.z;
            o.w = acc[mi][ni][3] + bi4.w;
            *(float4*)&op[(size_t)m*1536 + nbase] = o;
        }
    }
}

// ---------------- GRU weight repack (fp32, R8-proven) ----------------------
__global__ __launch_bounds__(256) void build_whhp_k(const float* __restrict__ whh,
        float4* __restrict__ whh_p)
{
    int idx = blockIdx.x*256 + threadIdx.x;   // < 512*512
    int i = idx >> 9, j = idx & 511;
    float4 o;
    o.x = whh[(size_t)j*512 + i];
    o.y = whh[(size_t)(512+j)*512 + i];
    o.z = whh[(size_t)(1024+j)*512 + i];
    o.w = 0.f;
    whh_p[idx] = o;
}

// ---------------- persistent GRU: all 76 steps, grid.sync between ----------
// 64 blocks x 1024 threads (co-resident); s=0 state is zero (no memset needed)
__global__ __launch_bounds__(1024) void gru_all_k(const float4* __restrict__ whh_p,
        const float* __restrict__ xg, const float* __restrict__ bhh,
        float* __restrict__ outs, int nsplit)
{
    cg::grid_group grid = cg::this_grid();
    __shared__ float hl[2048];
    __shared__ float red[4][4][64][3];
    int t = threadIdx.x;
    int jc = blockIdx.x & 7, bq = blockIdx.x >> 3;
    int jl = t & 63, bl = (t >> 6) & 3, iq = t >> 8;
    int j = jc*64 + jl;
    const float4* wp0 = whh_p + (size_t)(iq*128)*512 + j;

    for (int s=0; s<76; ++s){
        for (int idx=t; idx<2048; idx+=1024)
            hl[idx] = (s == 0) ? 0.f
                : outs[(size_t)s*16384 + (size_t)(bq*4 + (idx>>9))*512 + (idx&511)];
        __syncthreads();
        float a0=0.f,a1=0.f,a2=0.f;
        const float* hb = hl + bl*512 + iq*128;
        #pragma unroll 4
        for (int i=0;i<128;++i){
            float4 w4 = wp0[(size_t)i*512];
            float hv = hb[i];
            a0 += w4.x*hv; a1 += w4.y*hv; a2 += w4.z*hv;
        }
        red[iq][bl][jl][0] = a0; red[iq][bl][jl][1] = a1; red[iq][bl][jl][2] = a2;
        __syncthreads();
        if (t < 256){
            int jl2 = t & 63, bl2 = t >> 6;
            int j2 = jc*64 + jl2, b = bq*4 + bl2;
            float hr=0.f, hz=0.f, hn=0.f;
            #pragma unroll
            for (int q=0;q<4;++q){
                hr += red[q][bl2][jl2][0];
                hz += red[q][bl2][jl2][1];
                hn += red[q][bl2][jl2][2];
            }
            size_t xi = (size_t)(s*32 + b)*1536 + j2;
            float xr = xg[xi], xz = xg[xi+512], xn = xg[xi+1024];
            if (nsplit == 2){
                xr += xg[xi + XG_STRIDE];
                xz += xg[xi + 512 + XG_STRIDE];
                xn += xg[xi + 1024 + XG_STRIDE];
            }
            hr += bhh[j2]; hz += bhh[512+j2]; hn += bhh[1024+j2];
            float r = sigm(xr+hr), z = sigm(xz+hz);
            float n = tanhf(xn + r*hn);
            float hp = hl[bl2*512 + j2];
            float hnew = (1.f - z)*n + z*hp;
            outs[(size_t)(s+1)*16384 + (size_t)b*512 + j2] = hnew;
        }
        __threadfence();
        grid.sync();
    }
}

// ---------------- final attention pooling over s ---------------------------
__global__ __launch_bounds__(256) void pool_k(const float* __restrict__ outs,
        const float* __restrict__ fcw, const float* __restrict__ fcb,
        float* __restrict__ out)
{
    __shared__ float att[80], watt[128];
    int b = blockIdx.x, t = threadIdx.x;
    int w = t >> 6, lane = t & 63;
    for (int s = w; s < 76; s += 4){
        float acc = 0.f;
        const float* op = outs + (size_t)(s+1)*16384 + (size_t)b*512;
        #pragma unroll
        for (int hh = 0; hh < 512; hh += 64) acc += op[hh+lane]*fcw[hh+lane];
        #pragma unroll
        for (int off=32; off; off>>=1) acc += __shfl_down(acc, off);
        if (lane==0) att[s] = acc + fcb[0];
    }
    __syncthreads();
    if (t < 64){
        float a0 = (t<76)? att[t] : -1e30f;
        float a1 = (t+64<76)? att[t+64] : -1e30f;
        float m = fmaxf(a0,a1);
        #pragma unroll
        for (int off=32; off; off>>=1) m = fmaxf(m, __shfl_xor(m, off));
        float e0 = (t<76)? __expf(a0-m) : 0.f;
        float e1 = (t+64<76)? __expf(a1-m) : 0.f;
        float ssum = e0+e1;
        #pragma unroll
        for (int off=32; off; off>>=1) ssum += __shfl_xor(ssum, off);
        float ri = 1.f/ssum;
        watt[t] = e0*ri;
        watt[t+64] = e1*ri;
    }
    __syncthreads();
    for (int h = t; h < 512; h += 256){
        float acc=0.f;
        for (int s=0;s<76;++s) acc += watt[s]*outs[(size_t)(s+1)*16384 + (size_t)b*512 + h];
        out[(size_t)b*512 + h] = acc;
    }
}

// ---------------- launch ----------------------------------------------------
extern "C" void kernel_launch(void* const* d_in, const int* in_sizes, int n_in,
                              void* d_out, int out_size, void* d_ws, size_t ws_size,
                              hipStream_t stream)
{
    const float* x   = (const float*)d_in[0];
    const float* w1  = (const float*)d_in[1];  const float* b1  = (const float*)d_in[2];
    const float* w2  = (const float*)d_in[3];  const float* b2  = (const float*)d_in[4];
    const float* w3  = (const float*)d_in[5];  const float* b3  = (const float*)d_in[6];
    const float* w4  = (const float*)d_in[7];  const float* b4  = (const float*)d_in[8];
    const float* wq  = (const float*)d_in[9];  const float* wk  = (const float*)d_in[10];
    const float* wv  = (const float*)d_in[11]; const float* wv1 = (const float*)d_in[12];
    const float* gamma = (const float*)d_in[13];
    const float* wih = (const float*)d_in[14]; const float* whh = (const float*)d_in[15];
    const float* bih = (const float*)d_in[16]; const float* bhh = (const float*)d_in[17];
    const float* fcw = (const float*)d_in[18]; const float* fcb = (const float*)d_in[19];

    // adaptive (nb, nsplit) by workspace; split-K = fixed 2-term ordered sum.
    int nb = 2, ns = 1;
    {
        auto need = [](int nb_, int ns_)->size_t{
            return ((size_t)nb_*4521984ull + 16117760ull
                    + (size_t)(ns_-1)*3735552ull)*4ull + 4096ull;
        };
        if      (ws_size >= need(8,2)){ nb = 8; ns = 2; }
        else if (ws_size >= need(4,2)){ nb = 4; ns = 2; }
        else if (ws_size >= need(2,2)){ nb = 2; ns = 2; }
    }

    float* ws = (float*)d_ws;
    size_t off = 0;
    size_t szAh = (size_t)nb*983040ull;   // nb*240*8192 us in fl units
    size_t szBh = (size_t)nb*966656ull;   // nb*236*8192 us in fl units
    size_t szP  = (size_t)nb*622592ull;   // nb*76*64*128 fp32
    unsigned short* bufAh = (unsigned short*)(ws + off); off += szAh;
    unsigned short* bufAl = (unsigned short*)(ws + off); off += szAh;
    unsigned short* bufBh = (unsigned short*)(ws + off); off += szBh;
    unsigned short* bufBl = (unsigned short*)(ws + off); off += szBh;
    float* V1b = ws + off; off += szP;
    unsigned short* seq_bf = (unsigned short*)(ws + off); off += 9961472ull; // 2432*8192 bf16
    float* xg   = ws + off; off += (size_t)ns*XG_STRIDE;   // split-K partials
    float* outs = ws + off; off += 77ull*16384;
    float4* whh_p = (float4*)(ws + off); off += 1048576ull; // 512*512 f4
    unsigned short* wbf_h = (unsigned short*)(ws + off); off += 30720ull;
    unsigned short* wbf_l = (unsigned short*)(ws + off); off += 30720ull;
    unsigned short* wr_h  = (unsigned short*)(ws + off); off += 24576ull;
    unsigned short* wr_l  = (unsigned short*)(ws + off); off += 24576ull;

    // F/G/V fp32 overlay on dead bufA pair (3*szP <= 2*szAh for all nb)
    float* Fb = (float*)bufAh;
    float* Gb = Fb + szP;
    float* Vb = Fb + 2*szP;
    // wih_bf overlays bufA+bufB after the loop (needs 6,291,456 fl <= 2*(szAh+szBh))
    unsigned short* wih_bf = bufAh;

    repack_convw_k<<<240, 256, 0, stream>>>(w2, w3, w4, wbf_h, wbf_l);
    repack_wrep_k<<<192, 256, 0, stream>>>(wq, wk, wv, wv1, wr_h, wr_l);
    build_whhp_k<<<1024, 256, 0, stream>>>(whh, whh_p);

    int nchunks = 32 / nb;
    for (int chunk=0; chunk<nchunks; ++chunk){
        int b_base = chunk*nb;
        conv1_k<<<nb*120, 256, 0, stream>>>(x, bufAh, bufAl, w1, b1, b_base);
        conv_mfma_s<<<236*nb*2, 256, 0, stream>>>(bufAh, bufAl, bufBh, bufBl,
                                                  wbf_h, wbf_l, b2, 240, 236);
        conv_mfma_s<<<232*nb*2, 256, 0, stream>>>(bufBh, bufBl, bufAh, bufAl,
                                                  wbf_h+20480, wbf_l+20480, b3, 236, 232);
        conv_mfma_s<<<228*nb*2, 256, 0, stream>>>(bufAh, bufAl, bufBh, bufBl,
                                                  wbf_h+40960, wbf_l+40960, b4, 232, 228);
        project_mfma_s<<<76*nb*8, 256, 0, stream>>>(bufBh, bufBl, wr_h, wr_l,
                                                    Fb, Gb, Vb, V1b);
        attend_k<<<dim3(76,nb), 256, 0, stream>>>(Fb, Gb, Vb, V1b, gamma, seq_bf, b_base);
    }
    conv_wih_bf16<<<12288, 256, 0, stream>>>(wih, wih_bf);
    gemm_xg_mfma<<<228*ns, 512, 0, stream>>>(seq_bf, wih_bf, bih, xg, ns);

    {
        void* gargs[] = { (void*)&whh_p, (void*)&xg, (void*)&bhh,
                          (void*)&outs, (void*)&ns };
        hipLaunchCooperativeKernel(reinterpret_cast<void*>(gru_all_k),
                                   dim3(64), dim3(1024), gargs, 0, stream);
    }
    pool_k<<<32, 256, 0, stream>>>(outs, fcw, fcb, (float*)d_out);
}

// Round 16
// 4055.355 us; speedup vs baseline: 1.1531x; 1.1531x over previous
//
#include <hip/hip_runtime.h>
#include <math.h>

// ---------------- problem constants ----------------
// B=32 in chunks of nb (adaptive by ws_size), L=244, C=128, F=64, KS=5
// conv lengths: 244 -> 240 -> 236 -> 232 -> 228 ; S=76 ; F3=192 ; D_SA=64
// HID=512, 3*HID=1536 ; big GEMM: M=2432, K=8192, N=1536 (split-K=2)
// R16 = R14 front-end/gemm (proven, ns<=2) + GRU restructured as ONE plain
// kernel: 32 blocks (one per batch), 76 steps block-locally (h in LDS, no
// grid sync, no launch gaps), pool fused into its epilogue.
// R15 measured the 76-launch GRU tail at ~1.46 ms; this removes it.

typedef __attribute__((ext_vector_type(8))) short short8;
typedef __attribute__((ext_vector_type(4))) float f32x4;

#define XG_STRIDE 3735552ull   // 2432*1536 floats per split-K partial

__device__ inline float sigm(float x){ return 1.f/(1.f+__expf(-x)); }
__device__ inline unsigned short f2bf(float f){
    unsigned int u = __float_as_uint(f);
    u = (u + 0x7FFFu + ((u >> 16) & 1u)) >> 16;
    return (unsigned short)u;
}
__device__ inline float bf2f(unsigned short h){
    return __uint_as_float(((unsigned int)h) << 16);
}
// bijective chunked XCD swizzle (m204): contiguous work ranges per XCD
__device__ inline int xcd_chunked(int orig, int nwg){
    int q = nwg >> 3, r = nwg & 7;
    int xcd = orig & 7, i = orig >> 3;
    return (xcd < r ? xcd*(q+1) : r*(q+1) + (xcd-r)*q) + i;
}

// ---------------- conv1: x[b][l][c] fp32 -> h1 pair [b][l][c][f] -----------
__global__ __launch_bounds__(256) void conv1_k(const float* __restrict__ x,
        unsigned short* __restrict__ out_h, unsigned short* __restrict__ out_l,
        const float* __restrict__ w1, const float* __restrict__ b1, int b_base)
{
    __shared__ float w1s[320];
    __shared__ float b1s[64];
    int t = threadIdx.x;
    for (int idx = t; idx < 320; idx += 256) w1s[idx] = w1[idx];
    if (t < 64)  b1s[t] = b1[t];
    __syncthreads();
    int i = blockIdx.x*256 + t;          // < nb*240*128
    int c = i & 127; int t2 = i >> 7;
    int l = t2 % 240; int b = t2 / 240;
    const float* xp = x + ((size_t)(b_base + b)*244 + l)*128 + c;
    float xv[5];
    #pragma unroll
    for (int k=0;k<5;++k) xv[k] = xp[k*128];
    unsigned short* oh = out_h + (size_t)i*64;
    unsigned short* ol = out_l + (size_t)i*64;
    #pragma unroll
    for (int f8=0; f8<8; ++f8){
        unsigned short rh[8], rl[8];
        #pragma unroll
        for (int j=0;j<8;++j){
            int f = f8*8 + j;
            float a = b1s[f];
            #pragma unroll
            for (int k=0;k<5;++k) a += w1s[f*5+k]*xv[k];
            a = a > 0.f ? a : 0.f;
            unsigned short hi = f2bf(a);
            rh[j] = hi;
            rl[j] = f2bf(a - bf2f(hi));
        }
        *(short8*)(oh + f8*8) = *(short8*)rh;
        *(short8*)(ol + f8*8) = *(short8*)rl;
    }
}

// ---------------- conv weight repack pairs: [layer][k][fo][fi] -------------
__global__ __launch_bounds__(256) void repack_convw_k(const float* __restrict__ w2,
        const float* __restrict__ w3, const float* __restrict__ w4,
        unsigned short* __restrict__ wbf_h, unsigned short* __restrict__ wbf_l)
{
    int idx = blockIdx.x*256 + threadIdx.x;   // < 61440
    int fi = idx & 63; int t2 = idx >> 6;
    int fo = t2 & 63;  int t3 = t2 >> 6;
    int k = t3 % 5;    int layer = t3 / 5;
    const float* ws_ = (layer==0)? w2 : (layer==1)? w3 : w4;
    float v = ws_[(fo*64 + fi)*5 + k];
    unsigned short hi = f2bf(v);
    wbf_h[idx] = hi;
    wbf_l[idx] = f2bf(v - bf2f(hi));
}

// ---------------- conv2/3/4 split MFMA (R12-proven body, swizzled 1D grid) -
__global__ __launch_bounds__(256) void conv_mfma_s(
        const unsigned short* __restrict__ in_h, const unsigned short* __restrict__ in_l,
        unsigned short* __restrict__ out_h, unsigned short* __restrict__ out_l,
        const unsigned short* __restrict__ wk_h, const unsigned short* __restrict__ wk_l,
        const float* __restrict__ bias, int Lin, int Lout)
{
    __shared__ __align__(16) unsigned short Abh[64*72], Abl[64*72];
    __shared__ __align__(16) unsigned short Wbh[64*72], Wbl[64*72];
    int nblk = gridDim.x;
    int lin = xcd_chunked(blockIdx.x, nblk);
    int ch = lin & 1; int rest = lin >> 1;
    int l = rest % Lout; int b = rest / Lout;

    int t = threadIdx.x;
    int lane = t & 63, w = t >> 6;
    int lr = lane & 15, lh = lane >> 4;
    f32x4 acc[4];
    #pragma unroll
    for (int nf=0;nf<4;++nf) acc[nf] = (f32x4)0.f;

    const size_t ib = ((size_t)b*Lin + l)*8192 + (size_t)ch*4096;
    for (int k=0;k<5;++k){
        __syncthreads();
        #pragma unroll
        for (int i=0;i<2;++i){
            int idx = i*256 + t; int row = idx>>3, c8 = idx&7;
            *(short8*)&Abh[row*72 + c8*8] = *(const short8*)(in_h + ib + (size_t)k*8192 + idx*8);
            *(short8*)&Abl[row*72 + c8*8] = *(const short8*)(in_l + ib + (size_t)k*8192 + idx*8);
        }
        #pragma unroll
        for (int i=0;i<2;++i){
            int idx = i*256 + t; int row = idx>>3, c8 = idx&7;
            *(short8*)&Wbh[row*72 + c8*8] = *(const short8*)(wk_h + k*4096 + idx*8);
            *(short8*)&Wbl[row*72 + c8*8] = *(const short8*)(wk_l + k*4096 + idx*8);
        }
        __syncthreads();
        #pragma unroll
        for (int kk=0;kk<2;++kk){
            short8 ah, al, bh[4], blo[4];
            ah = *(const short8*)&Abh[(w*16+lr)*72 + kk*32 + lh*8];
            al = *(const short8*)&Abl[(w*16+lr)*72 + kk*32 + lh*8];
            #pragma unroll
            for (int nf=0;nf<4;++nf){
                bh[nf]  = *(const short8*)&Wbh[(nf*16+lr)*72 + kk*32 + lh*8];
                blo[nf] = *(const short8*)&Wbl[(nf*16+lr)*72 + kk*32 + lh*8];
            }
            #pragma unroll
            for (int nf=0;nf<4;++nf){
                acc[nf] = __builtin_amdgcn_mfma_f32_16x16x32_bf16(ah, bh[nf],  acc[nf], 0,0,0);
                acc[nf] = __builtin_amdgcn_mfma_f32_16x16x32_bf16(ah, blo[nf], acc[nf], 0,0,0);
                acc[nf] = __builtin_amdgcn_mfma_f32_16x16x32_bf16(al, bh[nf],  acc[nf], 0,0,0);
            }
        }
    }
    const size_t ob = ((size_t)b*Lout + l)*8192;
    #pragma unroll
    for (int nf=0;nf<4;++nf){
        int fo = nf*16 + lr;
        float bv = bias[fo];
        #pragma unroll
        for (int q=0;q<4;++q){
            int c = ch*64 + w*16 + lh*4 + q;
            float v = acc[nf][q] + bv;
            v = v > 0.f ? v : 0.f;
            unsigned short hi = f2bf(v);
            out_h[ob + c*64 + fo] = hi;
            out_l[ob + c*64 + fo] = f2bf(v - bf2f(hi));
        }
    }
}

// ---------------- attention weight repack pairs: [md][jj*64+f] -------------
__global__ __launch_bounds__(256) void repack_wrep_k(const float* __restrict__ wq,
        const float* __restrict__ wk, const float* __restrict__ wv,
        const float* __restrict__ wv1,
        unsigned short* __restrict__ wr_h, unsigned short* __restrict__ wr_l)
{
    int idx = blockIdx.x*256 + threadIdx.x;   // < 256*192
    int ko = idx % 192; int md = idx / 192;
    int m = md >> 6, d = md & 63;
    int jj = ko >> 6, f = ko & 63;
    const float* src = (m==0)? wq : (m==1)? wk : (m==2)? wv : wv1;
    float v = src[d*192 + f*3 + jj];
    unsigned short hi = f2bf(v);
    wr_h[idx] = hi;
    wr_l[idx] = f2bf(v - bf2f(hi));
}

// ---------------- projection split MFMA (R12-proven body, swizzled 1D) -----
__global__ __launch_bounds__(256) void project_mfma_s(
        const unsigned short* __restrict__ h_h, const unsigned short* __restrict__ h_l,
        const unsigned short* __restrict__ wr_h, const unsigned short* __restrict__ wr_l,
        float* __restrict__ Fo, float* __restrict__ Go,
        float* __restrict__ Vo, float* __restrict__ V1o)
{
    __shared__ __align__(16) unsigned short Abh[64*72], Abl[64*72];
    __shared__ __align__(16) unsigned short Bbh[64*72], Bbl[64*72];
    int nblk = gridDim.x;
    int lin = xcd_chunked(blockIdx.x, nblk);
    int z = lin & 7; int rest = lin >> 3;
    int s = rest % 76; int bl = rest / 76;
    int mz = z >> 1, mh = z & 1;

    int t = threadIdx.x;
    int lane = t & 63, w = t >> 6;
    int wm = w >> 1, wn = w & 1;
    int lr = lane & 15, lh = lane >> 4;
    f32x4 acc[2][2];
    #pragma unroll
    for (int mf=0;mf<2;++mf)
        #pragma unroll
        for (int nf=0;nf<2;++nf) acc[mf][nf] = (f32x4)0.f;

    for (int jj=0;jj<3;++jj){
        __syncthreads();
        const size_t ao_ = ((size_t)bl*228 + 3*s + jj)*8192 + (size_t)mh*4096;
        #pragma unroll
        for (int i=0;i<2;++i){
            int idx = i*256 + t; int row = idx>>3, c8 = idx&7;
            *(short8*)&Abh[row*72 + c8*8] = *(const short8*)(h_h + ao_ + idx*8);
            *(short8*)&Abl[row*72 + c8*8] = *(const short8*)(h_l + ao_ + idx*8);
        }
        #pragma unroll
        for (int i=0;i<2;++i){
            int idx = i*256 + t; int row = idx>>3, c8 = idx&7;
            size_t wo = (size_t)(mz*64 + row)*192 + jj*64 + c8*8;
            *(short8*)&Bbh[row*72 + c8*8] = *(const short8*)(wr_h + wo);
            *(short8*)&Bbl[row*72 + c8*8] = *(const short8*)(wr_l + wo);
        }
        __syncthreads();
        #pragma unroll
        for (int kk=0;kk<2;++kk){
            short8 ah[2], al[2], bh[2], blo[2];
            #pragma unroll
            for (int mf=0;mf<2;++mf){
                ah[mf] = *(const short8*)&Abh[(wm*32+mf*16+lr)*72 + kk*32 + lh*8];
                al[mf] = *(const short8*)&Abl[(wm*32+mf*16+lr)*72 + kk*32 + lh*8];
            }
            #pragma unroll
            for (int nf=0;nf<2;++nf){
                bh[nf]  = *(const short8*)&Bbh[(wn*32+nf*16+lr)*72 + kk*32 + lh*8];
                blo[nf] = *(const short8*)&Bbl[(wn*32+nf*16+lr)*72 + kk*32 + lh*8];
            }
            #pragma unroll
            for (int mf=0;mf<2;++mf)
                #pragma unroll
                for (int nf=0;nf<2;++nf){
                    acc[mf][nf] = __builtin_amdgcn_mfma_f32_16x16x32_bf16(ah[mf], bh[nf],  acc[mf][nf], 0,0,0);
                    acc[mf][nf] = __builtin_amdgcn_mfma_f32_16x16x32_bf16(ah[mf], blo[nf], acc[mf][nf], 0,0,0);
                    acc[mf][nf] = __builtin_amdgcn_mfma_f32_16x16x32_bf16(al[mf], bh[nf],  acc[mf][nf], 0,0,0);
                }
        }
    }
    float* dst = (mz==0)? Fo : (mz==1)? Go : (mz==2)? Vo : V1o;
    size_t bs = (size_t)bl*76 + s;
    #pragma unroll
    for (int mf=0;mf<2;++mf)
        #pragma unroll
        for (int nf=0;nf<2;++nf){
            int d = wn*32 + nf*16 + lr;
            int c0 = mh*64 + wm*32 + mf*16 + lh*4;
            *(f32x4*)&dst[(bs*64 + d)*128 + c0] = acc[mf][nf];
        }
}

// ---------------- attention, fp32, 64KB LDS (R7-proven) --------------------
__global__ __launch_bounds__(256) void attend_k(const float* __restrict__ Fg,
        const float* __restrict__ Gg, const float* __restrict__ Vg,
        const float* __restrict__ V1g, const float* __restrict__ gamma,
        unsigned short* __restrict__ seq_bf, int b_base)
{
    __shared__ float sm[16384];    // exactly 64 KB
    int t = threadIdx.x;
    int s = blockIdx.x, bl = blockIdx.y;
    size_t base = ((size_t)bl*76 + s)*8192;
    for (int i=t; i<8192; i+=256) sm[i]      = Fg[base+i];
    for (int i=t; i<8192; i+=256) sm[8192+i] = Gg[base+i];
    __syncthreads();

    int k = t & 127, ch = t >> 7;
    float sc[64];
    #pragma unroll
    for (int j=0;j<64;++j) sc[j]=0.f;
    for (int d=0; d<64; ++d){
        float gk = sm[8192 + d*128 + k];
        #pragma unroll
        for (int cj=0; cj<16; ++cj){
            float4 f4 = *(const float4*)&sm[d*128 + ch*64 + cj*4];
            sc[cj*4+0] += f4.x*gk; sc[cj*4+1] += f4.y*gk;
            sc[cj*4+2] += f4.z*gk; sc[cj*4+3] += f4.w*gk;
        }
    }
    __syncthreads();
    float m = -1e30f;
    #pragma unroll
    for (int j=0;j<64;++j) m = fmaxf(m, sc[j]);
    sm[t] = m;
    for (int i=t; i<8192; i+=256) sm[8192+i] = Vg[base+i];
    __syncthreads();
    m = fmaxf(sm[k], sm[128+k]);
    float lsum = 0.f;
    #pragma unroll
    for (int j=0;j<64;++j){ sc[j] = __expf(sc[j]-m); lsum += sc[j]; }
    __syncthreads();
    sm[t] = lsum;
    __syncthreads();
    float rinv = 1.f/(sm[k] + sm[128+k]);
    #pragma unroll
    for (int j=0;j<64;++j) sc[j] *= rinv;
    __syncthreads();

    if (ch == 0){
        #pragma unroll
        for (int j=0;j<64;++j) sm[j*128 + k] = sc[j];
    }
    __syncthreads();

    int k2 = t & 31, dq = t >> 5;
    float ao[8][4];
    #pragma unroll
    for (int j=0;j<8;++j)
        #pragma unroll
        for (int mm=0;mm<4;++mm) ao[j][mm]=0.f;

    for (int c2=0; c2<64; ++c2){
        float bv0 = sm[c2*128 + k2],    bv1 = sm[c2*128 + k2+32];
        float bv2 = sm[c2*128 + k2+64], bv3 = sm[c2*128 + k2+96];
        #pragma unroll
        for (int j=0;j<8;++j){
            float v = sm[8192 + (dq*8+j)*128 + c2];
            ao[j][0]+=v*bv0; ao[j][1]+=v*bv1; ao[j][2]+=v*bv2; ao[j][3]+=v*bv3;
        }
    }
    __syncthreads();
    if (ch == 1){
        #pragma unroll
        for (int j=0;j<64;++j) sm[j*128 + k] = sc[j];
    }
    __syncthreads();
    for (int c2=64; c2<128; ++c2){
        float bv0 = sm[(c2-64)*128 + k2],    bv1 = sm[(c2-64)*128 + k2+32];
        float bv2 = sm[(c2-64)*128 + k2+64], bv3 = sm[(c2-64)*128 + k2+96];
        #pragma unroll
        for (int j=0;j<8;++j){
            float v = sm[8192 + (dq*8+j)*128 + c2];
            ao[j][0]+=v*bv0; ao[j][1]+=v*bv1; ao[j][2]+=v*bv2; ao[j][3]+=v*bv3;
        }
    }

    float gm = gamma[0];
    size_t sbase = (size_t)(s*32 + b_base + bl)*8192;
    #pragma unroll
    for (int j=0;j<8;++j){
        int d = dq*8+j;
        #pragma unroll
        for (int mm=0;mm<4;++mm){
            int kk = k2 + 32*mm;
            float val = gm*ao[j][mm] + V1g[base + (size_t)d*128 + kk];
            seq_bf[sbase + (size_t)d*128 + kk] = f2bf(val);
        }
    }
}

// ---------------- wih -> bf16 (identity) -----------------------------------
__global__ __launch_bounds__(256) void conv_wih_bf16(const float* __restrict__ w,
        unsigned short* __restrict__ o)
{
    int i = (blockIdx.x*256 + threadIdx.x)*4;   // < 1536*8192
    float4 v = *(const float4*)&w[i];
    ushort4 r;
    r.x = f2bf(v.x); r.y = f2bf(v.y); r.z = f2bf(v.z); r.w = f2bf(v.w);
    *(ushort4*)&o[i] = r;
}

// ---------------- big GEMM bf16 MFMA: 128x128, split-K partials (R11) ------
__global__ __launch_bounds__(512) void gemm_xg_mfma(const unsigned short* __restrict__ A,
        const unsigned short* __restrict__ Bw, const float* __restrict__ bih,
        float* __restrict__ out, int nsplit)
{
    __shared__ float AsF[128*36];
    __shared__ float BsF[128*36];
    int nwg = 228*nsplit;
    int wgid = xcd_chunked(blockIdx.x, nwg);
    int kz = wgid / 228;
    int r2 = wgid % 228;
    int n0 = (r2 % 12) * 128, m0 = (r2 / 12) * 128;   // m-major per XCD
    int klen = 8192 / nsplit;
    int kbase = kz * klen;
    int nkt = klen >> 6;

    int t = threadIdx.x;
    int w = t >> 6;                    // 0..7
    int wm = w >> 1, wn = w & 1;       // 4 x 2 wave grid; wave owns 32x64
    int lane = t & 63, lr = lane & 15, lh = lane >> 4;

    f32x4 acc[2][4];
    #pragma unroll
    for (int mi=0;mi<2;++mi)
        #pragma unroll
        for (int ni=0;ni<4;++ni) acc[mi][ni] = (f32x4)0.f;

    float4 ra[2], rb[2];
    #pragma unroll
    for (int i=0;i<2;++i){
        int idx = i*512 + t; int row = idx>>3, seg = idx&7;
        ra[i] = *(const float4*)(A  + (size_t)(m0 + row)*8192 + kbase + seg*8);
        rb[i] = *(const float4*)(Bw + (size_t)(n0 + row)*8192 + kbase + seg*8);
    }
    for (int kt=0; kt<nkt; ++kt){
        __syncthreads();
        #pragma unroll
        for (int i=0;i<2;++i){
            int idx = i*512 + t; int row = idx>>3, seg = idx&7;
            *(float4*)&AsF[row*36 + seg*4] = ra[i];
            *(float4*)&BsF[row*36 + seg*4] = rb[i];
        }
        __syncthreads();
        if (kt < nkt-1){
            int k0 = kbase + (kt+1)*64;
            #pragma unroll
            for (int i=0;i<2;++i){
                int idx = i*512 + t; int row = idx>>3, seg = idx&7;
                ra[i] = *(const float4*)(A  + (size_t)(m0 + row)*8192 + k0 + seg*8);
                rb[i] = *(const float4*)(Bw + (size_t)(n0 + row)*8192 + k0 + seg*8);
            }
        }
        #pragma unroll
        for (int kk=0;kk<2;++kk){
            short8 af[2], bf_[4];
            #pragma unroll
            for (int mi=0;mi<2;++mi)
                af[mi] = *(short8*)&AsF[(wm*32 + mi*16 + lr)*36 + kk*16 + lh*4];
            #pragma unroll
            for (int ni=0;ni<4;++ni)
                bf_[ni] = *(short8*)&BsF[(wn*64 + ni*16 + lr)*36 + kk*16 + lh*4];
            // operand-swapped: D fragment = C^T tile -> lane holds consecutive n
            #pragma unroll
            for (int mi=0;mi<2;++mi)
                #pragma unroll
                for (int ni=0;ni<4;++ni)
                    acc[mi][ni] = __builtin_amdgcn_mfma_f32_16x16x32_bf16(
                                      bf_[ni], af[mi], acc[mi][ni], 0, 0, 0);
        }
    }
    float* op = out + (size_t)kz*XG_STRIDE;
    #pragma unroll
    for (int ni=0;ni<4;++ni){
        int nbase = n0 + wn*64 + ni*16 + lh*4;
        float4 bi4 = (kz == 0) ? *(const float4*)&bih[nbase]
                               : make_float4(0.f,0.f,0.f,0.f);
        #pragma unroll
        for (int mi=0;mi<2;++mi){
            int m = m0 + wm*32 + mi*16 + lr;
            float4 o;
            o.x = acc[mi][ni][0] + bi4.x;
            o.y = acc[mi][ni][1] + bi4.y;
            o.z = acc[mi][ni][2] + bi4.z;
            o.w = acc[mi][ni][3] + bi4.w;
            *(float4*)&op[(size_t)m*1536 + nbase] = o;
        }
    }
}

// ---------------- GRU weight repack (fp32, R8-proven) ----------------------
__global__ __launch_bounds__(256) void build_whhp_k(const float* __restrict__ whh,
        float4* __restrict__ whh_p)
{
    int idx = blockIdx.x*256 + threadIdx.x;   // < 512*512
    int i = idx >> 9, j = idx & 511;
    float4 o;
    o.x = whh[(size_t)j*512 + i];
    o.y = whh[(size_t)(512+j)*512 + i];
    o.z = whh[(size_t)(1024+j)*512 + i];
    o.w = 0.f;
    whh_p[idx] = o;
}

// ---------------- GRU + pool: 32 blocks (one per batch), 76 steps ----------
// 1024 thr = 512 j x 2 i-halves ; h in LDS ; no cross-block deps.
__global__ __launch_bounds__(1024) void gru_pool_k(const float4* __restrict__ whh_p,
        const float* __restrict__ xg, const float* __restrict__ bhh,
        const float* __restrict__ fcw, const float* __restrict__ fcb,
        float* __restrict__ outs, float* __restrict__ out, int nsplit)
{
    __shared__ float hl[512];
    __shared__ float red[2][512][3];
    __shared__ float attl[80], watt[128];
    int b = blockIdx.x, t = threadIdx.x;
    int j = t & 511, ih = t >> 9;
    if (t < 512) hl[t] = 0.f;
    __syncthreads();
    const float4* wp = whh_p + (size_t)(ih*256)*512 + j;
    float bhr = bhh[j], bhz = bhh[512+j], bhn = bhh[1024+j];

    for (int s=0; s<76; ++s){
        float a0=0.f, a1=0.f, a2=0.f;
        const float* hb = hl + ih*256;
        #pragma unroll 8
        for (int i=0;i<256;++i){
            float4 w4 = wp[(size_t)i*512];
            float hv = hb[i];
            a0 += w4.x*hv; a1 += w4.y*hv; a2 += w4.z*hv;
        }
        red[ih][j][0]=a0; red[ih][j][1]=a1; red[ih][j][2]=a2;
        __syncthreads();
        if (ih == 0){
            float hr = red[0][j][0] + red[1][j][0] + bhr;
            float hz = red[0][j][1] + red[1][j][1] + bhz;
            float hn = red[0][j][2] + red[1][j][2] + bhn;
            size_t xi = (size_t)(s*32 + b)*1536 + j;
            float xr = xg[xi], xz = xg[xi+512], xn = xg[xi+1024];
            if (nsplit == 2){
                xr += xg[xi + XG_STRIDE];
                xz += xg[xi + 512 + XG_STRIDE];
                xn += xg[xi + 1024 + XG_STRIDE];
            }
            float r = sigm(xr+hr), z = sigm(xz+hz);
            float n = tanhf(xn + r*hn);
            float hp = hl[j];
            float hnew = (1.f - z)*n + z*hp;
            hl[j] = hnew;
            outs[(size_t)s*16384 + (size_t)b*512 + j] = hnew;
        }
        __syncthreads();
    }

    // ---- fused pooling (same summation order as the old pool_k) ----
    int w = t >> 6, lane = t & 63;
    for (int s = w; s < 76; s += 16){
        float acc = 0.f;
        const float* op = outs + (size_t)s*16384 + (size_t)b*512;
        #pragma unroll
        for (int hh = 0; hh < 512; hh += 64) acc += op[hh+lane]*fcw[hh+lane];
        #pragma unroll
        for (int off=32; off; off>>=1) acc += __shfl_down(acc, off);
        if (lane==0) attl[s] = acc + fcb[0];
    }
    __syncthreads();
    if (t < 64){
        float a0 = (t<76)? attl[t] : -1e30f;
        float a1 = (t+64<76)? attl[t+64] : -1e30f;
        float m = fmaxf(a0,a1);
        #pragma unroll
        for (int off=32; off; off>>=1) m = fmaxf(m, __shfl_xor(m, off));
        float e0 = (t<76)? __expf(a0-m) : 0.f;
        float e1 = (t+64<76)? __expf(a1-m) : 0.f;
        float ssum = e0+e1;
        #pragma unroll
        for (int off=32; off; off>>=1) ssum += __shfl_xor(ssum, off);
        float ri = 1.f/ssum;
        watt[t] = e0*ri;
        watt[t+64] = e1*ri;
    }
    __syncthreads();
    if (t < 512){
        float acc = 0.f;
        for (int s=0;s<76;++s) acc += watt[s]*outs[(size_t)s*16384 + (size_t)b*512 + t];
        out[(size_t)b*512 + t] = acc;
    }
}

// ---------------- launch ----------------------------------------------------
extern "C" void kernel_launch(void* const* d_in, const int* in_sizes, int n_in,
                              void* d_out, int out_size, void* d_ws, size_t ws_size,
                              hipStream_t stream)
{
    const float* x   = (const float*)d_in[0];
    const float* w1  = (const float*)d_in[1];  const float* b1  = (const float*)d_in[2];
    const float* w2  = (const float*)d_in[3];  const float* b2  = (const float*)d_in[4];
    const float* w3  = (const float*)d_in[5];  const float* b3  = (const float*)d_in[6];
    const float* w4  = (const float*)d_in[7];  const float* b4  = (const float*)d_in[8];
    const float* wq  = (const float*)d_in[9];  const float* wk  = (const float*)d_in[10];
    const float* wv  = (const float*)d_in[11]; const float* wv1 = (const float*)d_in[12];
    const float* gamma = (const float*)d_in[13];
    const float* wih = (const float*)d_in[14]; const float* whh = (const float*)d_in[15];
    const float* bih = (const float*)d_in[16]; const float* bhh = (const float*)d_in[17];
    const float* fcw = (const float*)d_in[18]; const float* fcb = (const float*)d_in[19];

    // adaptive (nb, nsplit) by workspace; split-K = fixed 2-term ordered sum.
    int nb = 2, ns = 1;
    {
        auto need = [](int nb_, int ns_)->size_t{
            return ((size_t)nb_*4521984ull + 16117760ull
                    + (size_t)(ns_-1)*3735552ull)*4ull + 4096ull;
        };
        if      (ws_size >= need(8,2)){ nb = 8; ns = 2; }
        else if (ws_size >= need(4,2)){ nb = 4; ns = 2; }
        else if (ws_size >= need(2,2)){ nb = 2; ns = 2; }
    }

    float* ws = (float*)d_ws;
    size_t off = 0;
    size_t szAh = (size_t)nb*983040ull;   // nb*240*8192 us in fl units
    size_t szBh = (size_t)nb*966656ull;   // nb*236*8192 us in fl units
    size_t szP  = (size_t)nb*622592ull;   // nb*76*64*128 fp32
    unsigned short* bufAh = (unsigned short*)(ws + off); off += szAh;
    unsigned short* bufAl = (unsigned short*)(ws + off); off += szAh;
    unsigned short* bufBh = (unsigned short*)(ws + off); off += szBh;
    unsigned short* bufBl = (unsigned short*)(ws + off); off += szBh;
    float* V1b = ws + off; off += szP;
    unsigned short* seq_bf = (unsigned short*)(ws + off); off += 9961472ull; // 2432*8192 bf16
    float* xg   = ws + off; off += (size_t)ns*XG_STRIDE;   // split-K partials
    float* outs = ws + off; off += 77ull*16384;
    float4* whh_p = (float4*)(ws + off); off += 1048576ull; // 512*512 f4
    unsigned short* wbf_h = (unsigned short*)(ws + off); off += 30720ull;
    unsigned short* wbf_l = (unsigned short*)(ws + off); off += 30720ull;
    unsigned short* wr_h  = (unsigned short*)(ws + off); off += 24576ull;
    unsigned short* wr_l  = (unsigned short*)(ws + off); off += 24576ull;

    // F/G/V fp32 overlay on dead bufA pair (3*szP <= 2*szAh for all nb)
    float* Fb = (float*)bufAh;
    float* Gb = Fb + szP;
    float* Vb = Fb + 2*szP;
    // wih_bf overlays bufA+bufB after the loop (needs 6,291,456 fl <= 2*(szAh+szBh))
    unsigned short* wih_bf = bufAh;

    repack_convw_k<<<240, 256, 0, stream>>>(w2, w3, w4, wbf_h, wbf_l);
    repack_wrep_k<<<192, 256, 0, stream>>>(wq, wk, wv, wv1, wr_h, wr_l);
    build_whhp_k<<<1024, 256, 0, stream>>>(whh, whh_p);

    int nchunks = 32 / nb;
    for (int chunk=0; chunk<nchunks; ++chunk){
        int b_base = chunk*nb;
        conv1_k<<<nb*120, 256, 0, stream>>>(x, bufAh, bufAl, w1, b1, b_base);
        conv_mfma_s<<<236*nb*2, 256, 0, stream>>>(bufAh, bufAl, bufBh, bufBl,
                                                  wbf_h, wbf_l, b2, 240, 236);
        conv_mfma_s<<<232*nb*2, 256, 0, stream>>>(bufBh, bufBl, bufAh, bufAl,
                                                  wbf_h+20480, wbf_l+20480, b3, 236, 232);
        conv_mfma_s<<<228*nb*2, 256, 0, stream>>>(bufAh, bufAl, bufBh, bufBl,
                                                  wbf_h+40960, wbf_l+40960, b4, 232, 228);
        project_mfma_s<<<76*nb*8, 256, 0, stream>>>(bufBh, bufBl, wr_h, wr_l,
                                                    Fb, Gb, Vb, V1b);
        attend_k<<<dim3(76,nb), 256, 0, stream>>>(Fb, Gb, Vb, V1b, gamma, seq_bf, b_base);
    }
    conv_wih_bf16<<<12288, 256, 0, stream>>>(wih, wih_bf);
    gemm_xg_mfma<<<228*ns, 512, 0, stream>>>(seq_bf, wih_bf, bih, xg, ns);
    gru_pool_k<<<32, 1024, 0, stream>>>(whh_p, xg, bhh, fcw, fcb,
                                        outs, (float*)d_out, ns);
}

// Round 17
// 2674.269 us; speedup vs baseline: 1.7486x; 1.5164x over previous
//
#include <hip/hip_runtime.h>
#include <math.h>

// ---------------- problem constants ----------------
// B=32 in chunks of nb (adaptive by ws_size), L=244, C=128, F=64, KS=5
// conv lengths: 244 -> 240 -> 236 -> 232 -> 228 ; S=76 ; F3=192 ; D_SA=64
// HID=512, 3*HID=1536 ; big GEMM: M=2432, K=8192, N=1536 (split-K=2)
// R17 = R14 (2998us proven) with the GRU tail replaced: cooperative kernel,
// 64 blocks each owning 8 j's with the weight slice in LDS; custom
// sense-reversing device barrier between the 76 steps. GRU math/order
// bit-identical to R12's proven gru (4x128 i-split, ascending combine).

typedef __attribute__((ext_vector_type(8))) short short8;
typedef __attribute__((ext_vector_type(4))) float f32x4;

#define XG_STRIDE 3735552ull   // 2432*1536 floats per split-K partial

__device__ inline float sigm(float x){ return 1.f/(1.f+__expf(-x)); }
__device__ inline unsigned short f2bf(float f){
    unsigned int u = __float_as_uint(f);
    u = (u + 0x7FFFu + ((u >> 16) & 1u)) >> 16;
    return (unsigned short)u;
}
__device__ inline float bf2f(unsigned short h){
    return __uint_as_float(((unsigned int)h) << 16);
}
// bijective chunked XCD swizzle (m204): contiguous work ranges per XCD
__device__ inline int xcd_chunked(int orig, int nwg){
    int q = nwg >> 3, r = nwg & 7;
    int xcd = orig & 7, i = orig >> 3;
    return (xcd < r ? xcd*(q+1) : r*(q+1) + (xcd-r)*q) + i;
}

// ---------------- conv1: x[b][l][c] fp32 -> h1 pair [b][l][c][f] -----------
__global__ __launch_bounds__(256) void conv1_k(const float* __restrict__ x,
        unsigned short* __restrict__ out_h, unsigned short* __restrict__ out_l,
        const float* __restrict__ w1, const float* __restrict__ b1, int b_base)
{
    __shared__ float w1s[320];
    __shared__ float b1s[64];
    int t = threadIdx.x;
    for (int idx = t; idx < 320; idx += 256) w1s[idx] = w1[idx];
    if (t < 64)  b1s[t] = b1[t];
    __syncthreads();
    int i = blockIdx.x*256 + t;          // < nb*240*128
    int c = i & 127; int t2 = i >> 7;
    int l = t2 % 240; int b = t2 / 240;
    const float* xp = x + ((size_t)(b_base + b)*244 + l)*128 + c;
    float xv[5];
    #pragma unroll
    for (int k=0;k<5;++k) xv[k] = xp[k*128];
    unsigned short* oh = out_h + (size_t)i*64;
    unsigned short* ol = out_l + (size_t)i*64;
    #pragma unroll
    for (int f8=0; f8<8; ++f8){
        unsigned short rh[8], rl[8];
        #pragma unroll
        for (int j=0;j<8;++j){
            int f = f8*8 + j;
            float a = b1s[f];
            #pragma unroll
            for (int k=0;k<5;++k) a += w1s[f*5+k]*xv[k];
            a = a > 0.f ? a : 0.f;
            unsigned short hi = f2bf(a);
            rh[j] = hi;
            rl[j] = f2bf(a - bf2f(hi));
        }
        *(short8*)(oh + f8*8) = *(short8*)rh;
        *(short8*)(ol + f8*8) = *(short8*)rl;
    }
}

// ---------------- conv weight repack pairs: [layer][k][fo][fi] -------------
__global__ __launch_bounds__(256) void repack_convw_k(const float* __restrict__ w2,
        const float* __restrict__ w3, const float* __restrict__ w4,
        unsigned short* __restrict__ wbf_h, unsigned short* __restrict__ wbf_l)
{
    int idx = blockIdx.x*256 + threadIdx.x;   // < 61440
    int fi = idx & 63; int t2 = idx >> 6;
    int fo = t2 & 63;  int t3 = t2 >> 6;
    int k = t3 % 5;    int layer = t3 / 5;
    const float* ws_ = (layer==0)? w2 : (layer==1)? w3 : w4;
    float v = ws_[(fo*64 + fi)*5 + k];
    unsigned short hi = f2bf(v);
    wbf_h[idx] = hi;
    wbf_l[idx] = f2bf(v - bf2f(hi));
}

// ---------------- conv2/3/4 split MFMA (R12-proven body, swizzled 1D grid) -
__global__ __launch_bounds__(256) void conv_mfma_s(
        const unsigned short* __restrict__ in_h, const unsigned short* __restrict__ in_l,
        unsigned short* __restrict__ out_h, unsigned short* __restrict__ out_l,
        const unsigned short* __restrict__ wk_h, const unsigned short* __restrict__ wk_l,
        const float* __restrict__ bias, int Lin, int Lout)
{
    __shared__ __align__(16) unsigned short Abh[64*72], Abl[64*72];
    __shared__ __align__(16) unsigned short Wbh[64*72], Wbl[64*72];
    int nblk = gridDim.x;
    int lin = xcd_chunked(blockIdx.x, nblk);
    int ch = lin & 1; int rest = lin >> 1;
    int l = rest % Lout; int b = rest / Lout;

    int t = threadIdx.x;
    int lane = t & 63, w = t >> 6;
    int lr = lane & 15, lh = lane >> 4;
    f32x4 acc[4];
    #pragma unroll
    for (int nf=0;nf<4;++nf) acc[nf] = (f32x4)0.f;

    const size_t ib = ((size_t)b*Lin + l)*8192 + (size_t)ch*4096;
    for (int k=0;k<5;++k){
        __syncthreads();
        #pragma unroll
        for (int i=0;i<2;++i){
            int idx = i*256 + t; int row = idx>>3, c8 = idx&7;
            *(short8*)&Abh[row*72 + c8*8] = *(const short8*)(in_h + ib + (size_t)k*8192 + idx*8);
            *(short8*)&Abl[row*72 + c8*8] = *(const short8*)(in_l + ib + (size_t)k*8192 + idx*8);
        }
        #pragma unroll
        for (int i=0;i<2;++i){
            int idx = i*256 + t; int row = idx>>3, c8 = idx&7;
            *(short8*)&Wbh[row*72 + c8*8] = *(const short8*)(wk_h + k*4096 + idx*8);
            *(short8*)&Wbl[row*72 + c8*8] = *(const short8*)(wk_l + k*4096 + idx*8);
        }
        __syncthreads();
        #pragma unroll
        for (int kk=0;kk<2;++kk){
            short8 ah, al, bh[4], blo[4];
            ah = *(const short8*)&Abh[(w*16+lr)*72 + kk*32 + lh*8];
            al = *(const short8*)&Abl[(w*16+lr)*72 + kk*32 + lh*8];
            #pragma unroll
            for (int nf=0;nf<4;++nf){
                bh[nf]  = *(const short8*)&Wbh[(nf*16+lr)*72 + kk*32 + lh*8];
                blo[nf] = *(const short8*)&Wbl[(nf*16+lr)*72 + kk*32 + lh*8];
            }
            #pragma unroll
            for (int nf=0;nf<4;++nf){
                acc[nf] = __builtin_amdgcn_mfma_f32_16x16x32_bf16(ah, bh[nf],  acc[nf], 0,0,0);
                acc[nf] = __builtin_amdgcn_mfma_f32_16x16x32_bf16(ah, blo[nf], acc[nf], 0,0,0);
                acc[nf] = __builtin_amdgcn_mfma_f32_16x16x32_bf16(al, bh[nf],  acc[nf], 0,0,0);
            }
        }
    }
    const size_t ob = ((size_t)b*Lout + l)*8192;
    #pragma unroll
    for (int nf=0;nf<4;++nf){
        int fo = nf*16 + lr;
        float bv = bias[fo];
        #pragma unroll
        for (int q=0;q<4;++q){
            int c = ch*64 + w*16 + lh*4 + q;
            float v = acc[nf][q] + bv;
            v = v > 0.f ? v : 0.f;
            unsigned short hi = f2bf(v);
            out_h[ob + c*64 + fo] = hi;
            out_l[ob + c*64 + fo] = f2bf(v - bf2f(hi));
        }
    }
}

// ---------------- attention weight repack pairs: [md][jj*64+f] -------------
__global__ __launch_bounds__(256) void repack_wrep_k(const float* __restrict__ wq,
        const float* __restrict__ wk, const float* __restrict__ wv,
        const float* __restrict__ wv1,
        unsigned short* __restrict__ wr_h, unsigned short* __restrict__ wr_l)
{
    int idx = blockIdx.x*256 + threadIdx.x;   // < 256*192
    int ko = idx % 192; int md = idx / 192;
    int m = md >> 6, d = md & 63;
    int jj = ko >> 6, f = ko & 63;
    const float* src = (m==0)? wq : (m==1)? wk : (m==2)? wv : wv1;
    float v = src[d*192 + f*3 + jj];
    unsigned short hi = f2bf(v);
    wr_h[idx] = hi;
    wr_l[idx] = f2bf(v - bf2f(hi));
}

// ---------------- projection split MFMA (R12-proven body, swizzled 1D) -----
__global__ __launch_bounds__(256) void project_mfma_s(
        const unsigned short* __restrict__ h_h, const unsigned short* __restrict__ h_l,
        const unsigned short* __restrict__ wr_h, const unsigned short* __restrict__ wr_l,
        float* __restrict__ Fo, float* __restrict__ Go,
        float* __restrict__ Vo, float* __restrict__ V1o)
{
    __shared__ __align__(16) unsigned short Abh[64*72], Abl[64*72];
    __shared__ __align__(16) unsigned short Bbh[64*72], Bbl[64*72];
    int nblk = gridDim.x;
    int lin = xcd_chunked(blockIdx.x, nblk);
    int z = lin & 7; int rest = lin >> 3;
    int s = rest % 76; int bl = rest / 76;
    int mz = z >> 1, mh = z & 1;

    int t = threadIdx.x;
    int lane = t & 63, w = t >> 6;
    int wm = w >> 1, wn = w & 1;
    int lr = lane & 15, lh = lane >> 4;
    f32x4 acc[2][2];
    #pragma unroll
    for (int mf=0;mf<2;++mf)
        #pragma unroll
        for (int nf=0;nf<2;++nf) acc[mf][nf] = (f32x4)0.f;

    for (int jj=0;jj<3;++jj){
        __syncthreads();
        const size_t ao_ = ((size_t)bl*228 + 3*s + jj)*8192 + (size_t)mh*4096;
        #pragma unroll
        for (int i=0;i<2;++i){
            int idx = i*256 + t; int row = idx>>3, c8 = idx&7;
            *(short8*)&Abh[row*72 + c8*8] = *(const short8*)(h_h + ao_ + idx*8);
            *(short8*)&Abl[row*72 + c8*8] = *(const short8*)(h_l + ao_ + idx*8);
        }
        #pragma unroll
        for (int i=0;i<2;++i){
            int idx = i*256 + t; int row = idx>>3, c8 = idx&7;
            size_t wo = (size_t)(mz*64 + row)*192 + jj*64 + c8*8;
            *(short8*)&Bbh[row*72 + c8*8] = *(const short8*)(wr_h + wo);
            *(short8*)&Bbl[row*72 + c8*8] = *(const short8*)(wr_l + wo);
        }
        __syncthreads();
        #pragma unroll
        for (int kk=0;kk<2;++kk){
            short8 ah[2], al[2], bh[2], blo[2];
            #pragma unroll
            for (int mf=0;mf<2;++mf){
                ah[mf] = *(const short8*)&Abh[(wm*32+mf*16+lr)*72 + kk*32 + lh*8];
                al[mf] = *(const short8*)&Abl[(wm*32+mf*16+lr)*72 + kk*32 + lh*8];
            }
            #pragma unroll
            for (int nf=0;nf<2;++nf){
                bh[nf]  = *(const short8*)&Bbh[(wn*32+nf*16+lr)*72 + kk*32 + lh*8];
                blo[nf] = *(const short8*)&Bbl[(wn*32+nf*16+lr)*72 + kk*32 + lh*8];
            }
            #pragma unroll
            for (int mf=0;mf<2;++mf)
                #pragma unroll
                for (int nf=0;nf<2;++nf){
                    acc[mf][nf] = __builtin_amdgcn_mfma_f32_16x16x32_bf16(ah[mf], bh[nf],  acc[mf][nf], 0,0,0);
                    acc[mf][nf] = __builtin_amdgcn_mfma_f32_16x16x32_bf16(ah[mf], blo[nf], acc[mf][nf], 0,0,0);
                    acc[mf][nf] = __builtin_amdgcn_mfma_f32_16x16x32_bf16(al[mf], bh[nf],  acc[mf][nf], 0,0,0);
                }
        }
    }
    float* dst = (mz==0)? Fo : (mz==1)? Go : (mz==2)? Vo : V1o;
    size_t bs = (size_t)bl*76 + s;
    #pragma unroll
    for (int mf=0;mf<2;++mf)
        #pragma unroll
        for (int nf=0;nf<2;++nf){
            int d = wn*32 + nf*16 + lr;
            int c0 = mh*64 + wm*32 + mf*16 + lh*4;
            *(f32x4*)&dst[(bs*64 + d)*128 + c0] = acc[mf][nf];
        }
}

// ---------------- attention, fp32, 64KB LDS (R7-proven) --------------------
__global__ __launch_bounds__(256) void attend_k(const float* __restrict__ Fg,
        const float* __restrict__ Gg, const float* __restrict__ Vg,
        const float* __restrict__ V1g, const float* __restrict__ gamma,
        unsigned short* __restrict__ seq_bf, int b_base)
{
    __shared__ float sm[16384];    // exactly 64 KB
    int t = threadIdx.x;
    int s = blockIdx.x, bl = blockIdx.y;
    size_t base = ((size_t)bl*76 + s)*8192;
    for (int i=t; i<8192; i+=256) sm[i]      = Fg[base+i];
    for (int i=t; i<8192; i+=256) sm[8192+i] = Gg[base+i];
    __syncthreads();

    int k = t & 127, ch = t >> 7;
    float sc[64];
    #pragma unroll
    for (int j=0;j<64;++j) sc[j]=0.f;
    for (int d=0; d<64; ++d){
        float gk = sm[8192 + d*128 + k];
        #pragma unroll
        for (int cj=0; cj<16; ++cj){
            float4 f4 = *(const float4*)&sm[d*128 + ch*64 + cj*4];
            sc[cj*4+0] += f4.x*gk; sc[cj*4+1] += f4.y*gk;
            sc[cj*4+2] += f4.z*gk; sc[cj*4+3] += f4.w*gk;
        }
    }
    __syncthreads();
    float m = -1e30f;
    #pragma unroll
    for (int j=0;j<64;++j) m = fmaxf(m, sc[j]);
    sm[t] = m;
    for (int i=t; i<8192; i+=256) sm[8192+i] = Vg[base+i];
    __syncthreads();
    m = fmaxf(sm[k], sm[128+k]);
    float lsum = 0.f;
    #pragma unroll
    for (int j=0;j<64;++j){ sc[j] = __expf(sc[j]-m); lsum += sc[j]; }
    __syncthreads();
    sm[t] = lsum;
    __syncthreads();
    float rinv = 1.f/(sm[k] + sm[128+k]);
    #pragma unroll
    for (int j=0;j<64;++j) sc[j] *= rinv;
    __syncthreads();

    if (ch == 0){
        #pragma unroll
        for (int j=0;j<64;++j) sm[j*128 + k] = sc[j];
    }
    __syncthreads();

    int k2 = t & 31, dq = t >> 5;
    float ao[8][4];
    #pragma unroll
    for (int j=0;j<8;++j)
        #pragma unroll
        for (int mm=0;mm<4;++mm) ao[j][mm]=0.f;

    for (int c2=0; c2<64; ++c2){
        float bv0 = sm[c2*128 + k2],    bv1 = sm[c2*128 + k2+32];
        float bv2 = sm[c2*128 + k2+64], bv3 = sm[c2*128 + k2+96];
        #pragma unroll
        for (int j=0;j<8;++j){
            float v = sm[8192 + (dq*8+j)*128 + c2];
            ao[j][0]+=v*bv0; ao[j][1]+=v*bv1; ao[j][2]+=v*bv2; ao[j][3]+=v*bv3;
        }
    }
    __syncthreads();
    if (ch == 1){
        #pragma unroll
        for (int j=0;j<64;++j) sm[j*128 + k] = sc[j];
    }
    __syncthreads();
    for (int c2=64; c2<128; ++c2){
        float bv0 = sm[(c2-64)*128 + k2],    bv1 = sm[(c2-64)*128 + k2+32];
        float bv2 = sm[(c2-64)*128 + k2+64], bv3 = sm[(c2-64)*128 + k2+96];
        #pragma unroll
        for (int j=0;j<8;++j){
            float v = sm[8192 + (dq*8+j)*128 + c2];
            ao[j][0]+=v*bv0; ao[j][1]+=v*bv1; ao[j][2]+=v*bv2; ao[j][3]+=v*bv3;
        }
    }

    float gm = gamma[0];
    size_t sbase = (size_t)(s*32 + b_base + bl)*8192;
    #pragma unroll
    for (int j=0;j<8;++j){
        int d = dq*8+j;
        #pragma unroll
        for (int mm=0;mm<4;++mm){
            int kk = k2 + 32*mm;
            float val = gm*ao[j][mm] + V1g[base + (size_t)d*128 + kk];
            seq_bf[sbase + (size_t)d*128 + kk] = f2bf(val);
        }
    }
}

// ---------------- wih -> bf16 (identity) -----------------------------------
__global__ __launch_bounds__(256) void conv_wih_bf16(const float* __restrict__ w,
        unsigned short* __restrict__ o)
{
    int i = (blockIdx.x*256 + threadIdx.x)*4;   // < 1536*8192
    float4 v = *(const float4*)&w[i];
    ushort4 r;
    r.x = f2bf(v.x); r.y = f2bf(v.y); r.z = f2bf(v.z); r.w = f2bf(v.w);
    *(ushort4*)&o[i] = r;
}

// ---------------- big GEMM bf16 MFMA: 128x128, split-K partials (R11) ------
__global__ __launch_bounds__(512) void gemm_xg_mfma(const unsigned short* __restrict__ A,
        const unsigned short* __restrict__ Bw, const float* __restrict__ bih,
        float* __restrict__ out, int nsplit)
{
    __shared__ float AsF[128*36];
    __shared__ float BsF[128*36];
    int nwg = 228*nsplit;
    int wgid = xcd_chunked(blockIdx.x, nwg);
    int kz = wgid / 228;
    int r2 = wgid % 228;
    int n0 = (r2 % 12) * 128, m0 = (r2 / 12) * 128;   // m-major per XCD
    int klen = 8192 / nsplit;
    int kbase = kz * klen;
    int nkt = klen >> 6;

    int t = threadIdx.x;
    int w = t >> 6;                    // 0..7
    int wm = w >> 1, wn = w & 1;       // 4 x 2 wave grid; wave owns 32x64
    int lane = t & 63, lr = lane & 15, lh = lane >> 4;

    f32x4 acc[2][4];
    #pragma unroll
    for (int mi=0;mi<2;++mi)
        #pragma unroll
        for (int ni=0;ni<4;++ni) acc[mi][ni] = (f32x4)0.f;

    float4 ra[2], rb[2];
    #pragma unroll
    for (int i=0;i<2;++i){
        int idx = i*512 + t; int row = idx>>3, seg = idx&7;
        ra[i] = *(const float4*)(A  + (size_t)(m0 + row)*8192 + kbase + seg*8);
        rb[i] = *(const float4*)(Bw + (size_t)(n0 + row)*8192 + kbase + seg*8);
    }
    for (int kt=0; kt<nkt; ++kt){
        __syncthreads();
        #pragma unroll
        for (int i=0;i<2;++i){
            int idx = i*512 + t; int row = idx>>3, seg = idx&7;
            *(float4*)&AsF[row*36 + seg*4] = ra[i];
            *(float4*)&BsF[row*36 + seg*4] = rb[i];
        }
        __syncthreads();
        if (kt < nkt-1){
            int k0 = kbase + (kt+1)*64;
            #pragma unroll
            for (int i=0;i<2;++i){
                int idx = i*512 + t; int row = idx>>3, seg = idx&7;
                ra[i] = *(const float4*)(A  + (size_t)(m0 + row)*8192 + k0 + seg*8);
                rb[i] = *(const float4*)(Bw + (size_t)(n0 + row)*8192 + k0 + seg*8);
            }
        }
        #pragma unroll
        for (int kk=0;kk<2;++kk){
            short8 af[2], bf_[4];
            #pragma unroll
            for (int mi=0;mi<2;++mi)
                af[mi] = *(short8*)&AsF[(wm*32 + mi*16 + lr)*36 + kk*16 + lh*4];
            #pragma unroll
            for (int ni=0;ni<4;++ni)
                bf_[ni] = *(short8*)&BsF[(wn*64 + ni*16 + lr)*36 + kk*16 + lh*4];
            // operand-swapped: D fragment = C^T tile -> lane holds consecutive n
            #pragma unroll
            for (int mi=0;mi<2;++mi)
                #pragma unroll
                for (int ni=0;ni<4;++ni)
                    acc[mi][ni] = __builtin_amdgcn_mfma_f32_16x16x32_bf16(
                                      bf_[ni], af[mi], acc[mi][ni], 0, 0, 0);
        }
    }
    float* op = out + (size_t)kz*XG_STRIDE;
    #pragma unroll
    for (int ni=0;ni<4;++ni){
        int nbase = n0 + wn*64 + ni*16 + lh*4;
        float4 bi4 = (kz == 0) ? *(const float4*)&bih[nbase]
                               : make_float4(0.f,0.f,0.f,0.f);
        #pragma unroll
        for (int mi=0;mi<2;++mi){
            int m = m0 + wm*32 + mi*16 + lr;
            float4 o;
            o.x = acc[mi][ni][0] + bi4.x;
            o.y = acc[mi][ni][1] + bi4.y;
            o.z = acc[mi][ni][2] + bi4.z;
            o.w = acc[mi][ni][3] + bi4.w;
            *(float4*)&op[(size_t)m*1536 + nbase] = o;
        }
    }
}

// ---------------- GRU weight repack (fp32, R8-proven) ----------------------
__global__ __launch_bounds__(256) void build_whhp_k(const float* __restrict__ whh,
        float4* __restrict__ whh_p)
{
    int idx = blockIdx.x*256 + threadIdx.x;   // < 512*512
    int i = idx >> 9, j = idx & 511;
    float4 o;
    o.x = whh[(size_t)j*512 + i];
    o.y = whh[(size_t)(512+j)*512 + i];
    o.z = whh[(size_t)(1024+j)*512 + i];
    o.w = 0.f;
    whh_p[idx] = o;
}

// ---------------- persistent GRU: 64 blocks x 8 j's, weights in LDS --------
// custom sense-reversing device barrier between the 76 steps.
__global__ __launch_bounds__(1024) void gru_lds_k(const float4* __restrict__ whh_p,
        const float* __restrict__ xg, const float* __restrict__ bhh,
        float* __restrict__ outs, float* __restrict__ hbuf,
        int* __restrict__ bar, int nsplit)
{
    __shared__ float wlr[8][516], wlz[8][516], wln[8][516];   // 49.5 KB
    __shared__ float red[4][32][8][3];                        // 12 KB
    int t = threadIdx.x;
    int jc = blockIdx.x;                 // 0..63
    int j0 = jc*8;

    // stage this block's weight slice into LDS (once)
    #pragma unroll
    for (int it=0; it<4; ++it){
        int idx = it*1024 + t;           // < 4096
        int i = idx >> 3, jl = idx & 7;
        float4 w4 = whh_p[(size_t)i*512 + j0 + jl];
        wlr[jl][i] = w4.x; wlz[jl][i] = w4.y; wln[jl][i] = w4.z;
    }
    __syncthreads();

    int jl = t & 7, b = (t >> 3) & 31, iq = t >> 8;   // 8 x 32 x 4
    int volatile* cnt = bar;
    int volatile* gen = bar + 1;

    for (int s=0; s<76; ++s){
        float a0=0.f, a1=0.f, a2=0.f;
        if (s > 0){
            const float* hb = hbuf + ((s+1)&1)*16384 + b*512 + iq*128;
            const float* wr = &wlr[jl][iq*128];
            const float* wz = &wlz[jl][iq*128];
            const float* wn = &wln[jl][iq*128];
            #pragma unroll 4
            for (int i=0;i<128;++i){
                float hv = hb[i];
                a0 += wr[i]*hv; a1 += wz[i]*hv; a2 += wn[i]*hv;
            }
        }
        red[iq][b][jl][0]=a0; red[iq][b][jl][1]=a1; red[iq][b][jl][2]=a2;
        __syncthreads();
        if (t < 256){
            int jl2 = t & 7, b2 = t >> 3;
            int j2 = j0 + jl2;
            float hr=0.f, hz=0.f, hn=0.f;
            #pragma unroll
            for (int q=0;q<4;++q){
                hr += red[q][b2][jl2][0];
                hz += red[q][b2][jl2][1];
                hn += red[q][b2][jl2][2];
            }
            size_t xi = (size_t)(s*32 + b2)*1536 + j2;
            float xr = xg[xi], xz = xg[xi+512], xn = xg[xi+1024];
            if (nsplit == 2){
                xr += xg[xi + XG_STRIDE];
                xz += xg[xi + 512 + XG_STRIDE];
                xn += xg[xi + 1024 + XG_STRIDE];
            }
            hr += bhh[j2]; hz += bhh[512+j2]; hn += bhh[1024+j2];
            float r = sigm(xr+hr), z = sigm(xz+hz);
            float n = tanhf(xn + r*hn);
            float hp = (s==0) ? 0.f : hbuf[((s+1)&1)*16384 + b2*512 + j2];
            float hnew = (1.f - z)*n + z*hp;
            hbuf[(s&1)*16384 + (size_t)b2*512 + j2] = hnew;
            outs[(size_t)s*16384 + (size_t)b2*512 + j2] = hnew;
        }
        // ---- device barrier (sense-reversing, 2 atomics) ----
        __syncthreads();
        if (t == 0){
            __threadfence();
            int g = __hip_atomic_load((int*)gen, __ATOMIC_RELAXED,
                                      __HIP_MEMORY_SCOPE_AGENT);
            int arrived = __hip_atomic_fetch_add((int*)cnt, 1, __ATOMIC_ACQ_REL,
                                                 __HIP_MEMORY_SCOPE_AGENT);
            if (arrived == 63){
                __hip_atomic_store((int*)cnt, 0, __ATOMIC_RELAXED,
                                   __HIP_MEMORY_SCOPE_AGENT);
                __hip_atomic_fetch_add((int*)gen, 1, __ATOMIC_ACQ_REL,
                                       __HIP_MEMORY_SCOPE_AGENT);
            } else {
                while (__hip_atomic_load((int*)gen, __ATOMIC_ACQUIRE,
                                         __HIP_MEMORY_SCOPE_AGENT) == g)
                    __builtin_amdgcn_s_sleep(1);
            }
            __threadfence();
        }
        __syncthreads();
    }
}

// ---------------- final attention pooling over s (s-based outs) ------------
__global__ __launch_bounds__(256) void pool_k(const float* __restrict__ outs,
        const float* __restrict__ fcw, const float* __restrict__ fcb,
        float* __restrict__ out)
{
    __shared__ float att[80], watt[128];
    int b = blockIdx.x, t = threadIdx.x;
    int w = t >> 6, lane = t & 63;
    for (int s = w; s < 76; s += 4){
        float acc = 0.f;
        const float* op = outs + (size_t)s*16384 + (size_t)b*512;
        #pragma unroll
        for (int hh = 0; hh < 512; hh += 64) acc += op[hh+lane]*fcw[hh+lane];
        #pragma unroll
        for (int off=32; off; off>>=1) acc += __shfl_down(acc, off);
        if (lane==0) att[s] = acc + fcb[0];
    }
    __syncthreads();
    if (t < 64){
        float a0 = (t<76)? att[t] : -1e30f;
        float a1 = (t+64<76)? att[t+64] : -1e30f;
        float m = fmaxf(a0,a1);
        #pragma unroll
        for (int off=32; off; off>>=1) m = fmaxf(m, __shfl_xor(m, off));
        float e0 = (t<76)? __expf(a0-m) : 0.f;
        float e1 = (t+64<76)? __expf(a1-m) : 0.f;
        float ssum = e0+e1;
        #pragma unroll
        for (int off=32; off; off>>=1) ssum += __shfl_xor(ssum, off);
        float ri = 1.f/ssum;
        watt[t] = e0*ri;
        watt[t+64] = e1*ri;
    }
    __syncthreads();
    for (int h = t; h < 512; h += 256){
        float acc=0.f;
        for (int s=0;s<76;++s) acc += watt[s]*outs[(size_t)s*16384 + (size_t)b*512 + h];
        out[(size_t)b*512 + h] = acc;
    }
}

// ---------------- launch ----------------------------------------------------
extern "C" void kernel_launch(void* const* d_in, const int* in_sizes, int n_in,
                              void* d_out, int out_size, void* d_ws, size_t ws_size,
                              hipStream_t stream)
{
    const float* x   = (const float*)d_in[0];
    const float* w1  = (const float*)d_in[1];  const float* b1  = (const float*)d_in[2];
    const float* w2  = (const float*)d_in[3];  const float* b2  = (const float*)d_in[4];
    const float* w3  = (const float*)d_in[5];  const float* b3  = (const float*)d_in[6];
    const float* w4  = (const float*)d_in[7];  const float* b4  = (const float*)d_in[8];
    const float* wq  = (const float*)d_in[9];  const float* wk  = (const float*)d_in[10];
    const float* wv  = (const float*)d_in[11]; const float* wv1 = (const float*)d_in[12];
    const float* gamma = (const float*)d_in[13];
    const float* wih = (const float*)d_in[14]; const float* whh = (const float*)d_in[15];
    const float* bih = (const float*)d_in[16]; const float* bhh = (const float*)d_in[17];
    const float* fcw = (const float*)d_in[18]; const float* fcb = (const float*)d_in[19];

    // adaptive (nb, nsplit) by workspace; split-K = fixed 2-term ordered sum.
    int nb = 2, ns = 1;
    {
        auto need = [](int nb_, int ns_)->size_t{
            return ((size_t)nb_*4521984ull + 16117760ull
                    + (size_t)(ns_-1)*3735552ull + 40000ull)*4ull + 4096ull;
        };
        if      (ws_size >= need(8,2)){ nb = 8; ns = 2; }
        else if (ws_size >= need(4,2)){ nb = 4; ns = 2; }
        else if (ws_size >= need(2,2)){ nb = 2; ns = 2; }
    }

    float* ws = (float*)d_ws;
    size_t off = 0;
    size_t szAh = (size_t)nb*983040ull;   // nb*240*8192 us in fl units
    size_t szBh = (size_t)nb*966656ull;   // nb*236*8192 us in fl units
    size_t szP  = (size_t)nb*622592ull;   // nb*76*64*128 fp32
    unsigned short* bufAh = (unsigned short*)(ws + off); off += szAh;
    unsigned short* bufAl = (unsigned short*)(ws + off); off += szAh;
    unsigned short* bufBh = (unsigned short*)(ws + off); off += szBh;
    unsigned short* bufBl = (unsigned short*)(ws + off); off += szBh;
    float* V1b = ws + off; off += szP;
    unsigned short* seq_bf = (unsigned short*)(ws + off); off += 9961472ull; // 2432*8192 bf16
    float* xg   = ws + off; off += (size_t)ns*XG_STRIDE;   // split-K partials
    float* outs = ws + off; off += 77ull*16384;
    float4* whh_p = (float4*)(ws + off); off += 1048576ull; // 512*512 f4
    float* hbuf = ws + off; off += 32768ull;                // 2 x 32x512 fp32
    int* bar = (int*)(ws + off); off += 16ull;              // cnt, gen
    unsigned short* wbf_h = (unsigned short*)(ws + off); off += 30720ull;
    unsigned short* wbf_l = (unsigned short*)(ws + off); off += 30720ull;
    unsigned short* wr_h  = (unsigned short*)(ws + off); off += 24576ull;
    unsigned short* wr_l  = (unsigned short*)(ws + off); off += 24576ull;

    // F/G/V fp32 overlay on dead bufA pair (3*szP <= 2*szAh for all nb)
    float* Fb = (float*)bufAh;
    float* Gb = Fb + szP;
    float* Vb = Fb + 2*szP;
    // wih_bf overlays bufA+bufB after the loop (needs 6,291,456 fl <= 2*(szAh+szBh))
    unsigned short* wih_bf = bufAh;

    hipMemsetAsync(bar, 0, 8, stream);
    repack_convw_k<<<240, 256, 0, stream>>>(w2, w3, w4, wbf_h, wbf_l);
    repack_wrep_k<<<192, 256, 0, stream>>>(wq, wk, wv, wv1, wr_h, wr_l);
    build_whhp_k<<<1024, 256, 0, stream>>>(whh, whh_p);

    int nchunks = 32 / nb;
    for (int chunk=0; chunk<nchunks; ++chunk){
        int b_base = chunk*nb;
        conv1_k<<<nb*120, 256, 0, stream>>>(x, bufAh, bufAl, w1, b1, b_base);
        conv_mfma_s<<<236*nb*2, 256, 0, stream>>>(bufAh, bufAl, bufBh, bufBl,
                                                  wbf_h, wbf_l, b2, 240, 236);
        conv_mfma_s<<<232*nb*2, 256, 0, stream>>>(bufBh, bufBl, bufAh, bufAl,
                                                  wbf_h+20480, wbf_l+20480, b3, 236, 232);
        conv_mfma_s<<<228*nb*2, 256, 0, stream>>>(bufAh, bufAl, bufBh, bufBl,
                                                  wbf_h+40960, wbf_l+40960, b4, 232, 228);
        project_mfma_s<<<76*nb*8, 256, 0, stream>>>(bufBh, bufBl, wr_h, wr_l,
                                                    Fb, Gb, Vb, V1b);
        attend_k<<<dim3(76,nb), 256, 0, stream>>>(Fb, Gb, Vb, V1b, gamma, seq_bf, b_base);
    }
    conv_wih_bf16<<<12288, 256, 0, stream>>>(wih, wih_bf);
    gemm_xg_mfma<<<228*ns, 512, 0, stream>>>(seq_bf, wih_bf, bih, xg, ns);
    {
        void* gargs[] = { (void*)&whh_p, (void*)&xg, (void*)&bhh,
                          (void*)&outs, (void*)&hbuf, (void*)&bar, (void*)&ns };
        hipLaunchCooperativeKernel(reinterpret_cast<void*>(gru_lds_k),
                                   dim3(64), dim3(1024), gargs, 0, stream);
    }
    pool_k<<<32, 256, 0, stream>>>(outs, fcw, fcb, (float*)d_out);
}